// Round 11
// baseline (392.977 us; speedup 1.0000x reference)
//
#include <hip/hip_runtime.h>
#include <hip/hip_bf16.h>

// ModifiedGAT, round 22 (r21 resubmit; infra "container failed twice" with no
// verification result — same signature as r16 which passed verbatim later.
// One defensive change: g1b aliased into dead h0s upper half, returning the
// workspace footprint to the proven ~57.8MB envelope (r21 was 64.2MB).)
//  - XCD channel-slicing: h0 stored SLICE-MAJOR [8][N][32ch]; layer-0 agg
//    launched with slice p = blockIdx&7 -> under round-robin block->XCD
//    mapping each XCD only reads its 3.2MB slice (L2-resident). w/den
//    recomputed per slice (same esrc order). 8-lane groups, no LDS/barriers.
//  - gemm1 un-fused (r15: split ~= fused); A from 8 slice regions (k0>>5).
//  - Diagnostic: aggs FETCH ~60MB = win; ~200MB = XCD assumption wrong.
//  - Pipeline: memset | prep | blocksum | scan2 | scatter | gemm0 | aggs |
//              gemm1 | agg1g2 | aggF  (10 dispatches).

typedef unsigned short ushort_t;
typedef __attribute__((ext_vector_type(8))) short short8;
typedef __attribute__((ext_vector_type(4))) float f32x4;

__device__ __forceinline__ float elu_f(float x){ return x > 0.f ? x : expm1f(x); }
__device__ __forceinline__ float lrelu_f(float x){ return x > 0.f ? x : 0.2f * x; }
__device__ __forceinline__ ushort_t f2b(float f){
  union { float f; unsigned u; } v; v.f = f;
  unsigned r = v.u + 0x7fff + ((v.u >> 16) & 1);   // round-to-nearest-even
  return (ushort_t)(r >> 16);
}
__device__ __forceinline__ float b2f_lo(unsigned v){
  union { unsigned u; float f; } c; c.u = v << 16; return c.f;
}
__device__ __forceinline__ float b2f_hi(unsigned v){
  union { unsigned u; float f; } c; c.u = v & 0xffff0000u; return c.f;
}

// ---------------- prep: hist + weight transposes -----------------------------
__global__ __launch_bounds__(256) void prep_kernel(const int* __restrict__ ei,
                                                   int* __restrict__ cnt,
                                                   const float* __restrict__ W0,
                                                   ushort_t* __restrict__ W0p,
                                                   const float* __restrict__ W1,
                                                   ushort_t* __restrict__ W1p,
                                                   const float* __restrict__ W2,
                                                   ushort_t* __restrict__ W2p,
                                                   int E, int Etot, int eb){
  int bid = blockIdx.x; int t = threadIdx.x;
  if(bid < eb){
    int e = bid * 256 + t;
    if(e < Etot){
      int d = (e < E) ? ei[E + e] : (e - E);
      atomicAdd(&cnt[d], 1);
    }
  } else {
    int r = bid - eb;
    if(r < 256){            // W0: 256x256
      int i = r * 256 + t; int k = i >> 8, n = i & 255;
      W0p[(size_t)n * 256 + k] = f2b(W0[i]);
    } else if(r < 320){     // W1: 256x64
      int i = (r - 256) * 256 + t; int k = i >> 6, n = i & 63;
      W1p[(size_t)n * 256 + k] = f2b(W1[i]);
    } else {                // W2: 64x64
      int i = (r - 320) * 256 + t; int k = i >> 6, n = i & 63;
      W2p[(size_t)n * 64 + k] = f2b(W2[i]);
    }
  }
}

// ---------------- CSR scan -----------------------------------------------------
__global__ __launch_bounds__(256) void blocksum_kernel(const int* __restrict__ cnt,
                                                       int* __restrict__ bsum, int N){
  __shared__ int sm[256];
  int t = threadIdx.x;
  int i = blockIdx.x * 256 + t;
  sm[t] = (i < N) ? cnt[i] : 0;
  __syncthreads();
  for(int off = 128; off > 0; off >>= 1){
    if(t < off) sm[t] += sm[t + off];
    __syncthreads();
  }
  if(t == 0) bsum[blockIdx.x] = sm[0];
}

__global__ __launch_bounds__(256) void scan2_kernel(const int* __restrict__ cnt,
                                                    const int* __restrict__ bsum,
                                                    int* __restrict__ rowptr,
                                                    int* __restrict__ cursor,
                                                    int N, int Etot, int nb){
  __shared__ int sm[256];
  __shared__ int spfx;
  int t = threadIdx.x;
  int c = blockIdx.x;
  sm[t] = (t < c && t < nb) ? bsum[t] : 0;
  __syncthreads();
  for(int off = 128; off > 0; off >>= 1){
    if(t < off) sm[t] += sm[t + off];
    __syncthreads();
  }
  if(t == 0) spfx = sm[0];
  __syncthreads();
  int pfx = spfx;
  __syncthreads();
  int i = c * 256 + t;
  int v = (i < N) ? cnt[i] : 0;
  sm[t] = v;
  __syncthreads();
  for(int off = 1; off < 256; off <<= 1){
    int x = 0;
    if(t >= off) x = sm[t - off];
    __syncthreads();
    sm[t] += x;
    __syncthreads();
  }
  if(i < N){
    int ex = sm[t] - v + pfx;
    rowptr[i] = ex;
    cursor[i] = ex;
    if(i == N - 1) rowptr[N] = Etot;
  }
}

__global__ __launch_bounds__(256) void scatter_kernel(const int* __restrict__ ei,
                                                      int* __restrict__ cursor,
                                                      int* __restrict__ esrc,
                                                      int E, int Etot){
  int e = blockIdx.x * 256 + threadIdx.x;
  if(e >= Etot) return;
  int s, d;
  if(e < E){ s = ei[e]; d = ei[E + e]; } else { s = e - E; d = s; }
  int pos = atomicAdd(&cursor[d], 1);
  esrc[pos] = s;
}

// ---------------- GEMM0: h0s[8][M][32] = bf16(x @ W0) slice-major + logits ---
#define SKP 264   // padded LDS k-stride (shorts)
__global__ __launch_bounds__(256) void gemm0_kernel(const float4* __restrict__ x4,
                                                    const ushort_t* __restrict__ Bp,
                                                    ushort_t* __restrict__ h0s,
                                                    const float* __restrict__ asrc,
                                                    const float* __restrict__ adst,
                                                    float* __restrict__ als,
                                                    float* __restrict__ ald, int M){
  __shared__ ushort_t As[32 * SKP];
  int t = threadIdx.x;
  int row0 = blockIdx.x * 32;
  {
    int c = t;
    #pragma unroll
    for(int it = 0; it < 4; it++, c += 256){
      int r = c >> 5;
      int kc = (c & 31) << 3;
      int gr = row0 + r;
      short8 v = {};
      if(gr < M){
        float4 f0 = x4[(size_t)gr * 64 + (kc >> 2)];
        float4 f1 = x4[(size_t)gr * 64 + (kc >> 2) + 1];
        v[0] = (short)f2b(f0.x); v[1] = (short)f2b(f0.y);
        v[2] = (short)f2b(f0.z); v[3] = (short)f2b(f0.w);
        v[4] = (short)f2b(f1.x); v[5] = (short)f2b(f1.y);
        v[6] = (short)f2b(f1.z); v[7] = (short)f2b(f1.w);
      }
      *(short8*)(As + r * SKP + kc) = v;
    }
  }
  __syncthreads();
  int wave = t >> 6, lane = t & 63;
  int m = lane & 15, q = lane >> 4;
  int colb = wave;                   // head
  const ushort_t* Bq = Bp + (size_t)(colb * 64 + m) * 256 + q * 8;
  const ushort_t* A0 = As + m * SKP + q * 8;
  const ushort_t* A1 = As + (16 + m) * SKP + q * 8;
  f32x4 acc[2][4] = {};
  for(int k0 = 0; k0 < 256; k0 += 32){
    short8 bv[4];
    #pragma unroll
    for(int j = 0; j < 4; j++) bv[j] = *(const short8*)(Bq + (size_t)j * 16 * 256 + k0);
    short8 a0 = *(const short8*)(A0 + k0);
    short8 a1 = *(const short8*)(A1 + k0);
    #pragma unroll
    for(int j = 0; j < 4; j++){
      acc[0][j] = __builtin_amdgcn_mfma_f32_16x16x32_bf16(a0, bv[j], acc[0][j], 0, 0, 0);
      acc[1][j] = __builtin_amdgcn_mfma_f32_16x16x32_bf16(a1, bv[j], acc[1][j], 0, 0, 0);
    }
  }
  #pragma unroll
  for(int rt = 0; rt < 2; rt++){
    #pragma unroll
    for(int j = 0; j < 4; j++){
      int col = colb * 64 + j * 16 + m;
      size_t sbase = (size_t)(col >> 5) * M * 32;
      #pragma unroll
      for(int i = 0; i < 4; i++){
        int gr = row0 + rt * 16 + q * 4 + i;
        if(gr < M) h0s[sbase + (size_t)gr * 32 + (col & 31)] = f2b(acc[rt][j][i]);
      }
    }
    float vs[4] = {0,0,0,0}, vd[4] = {0,0,0,0};
    #pragma unroll
    for(int j = 0; j < 4; j++){
      int col = colb * 64 + j * 16 + m;
      float a_s = asrc[col], a_d = adst[col];
      #pragma unroll
      for(int i = 0; i < 4; i++){
        vs[i] = fmaf(acc[rt][j][i], a_s, vs[i]);
        vd[i] = fmaf(acc[rt][j][i], a_d, vd[i]);
      }
    }
    #pragma unroll
    for(int off = 8; off > 0; off >>= 1){
      #pragma unroll
      for(int i = 0; i < 4; i++){
        vs[i] += __shfl_down(vs[i], off, 16);
        vd[i] += __shfl_down(vd[i], off, 16);
      }
    }
    if(m == 0){
      #pragma unroll
      for(int i = 0; i < 4; i++){
        int gr = row0 + rt * 16 + q * 4 + i;
        if(gr < M){
          als[(size_t)gr * 4 + colb] = vs[i];
          ald[(size_t)gr * 4 + colb] = vd[i];
        }
      }
    }
  }
}

// ---------------- layer-0 agg, XCD channel-sliced ----------------------------
// slice p = blockIdx&7 (-> XCD p under round-robin); node group = blockIdx>>3.
// 8-lane group per node (4ch/lane, 64B slice row), 4 sequential nodes/group,
// 128 nodes/block, no LDS, no barriers. w/den recomputed per slice.
__global__ __launch_bounds__(256, 8) void aggs_kernel(const int* __restrict__ rowptr,
                                                      const int* __restrict__ esrc,
                                                      const uint2* __restrict__ h0s, // [8][N][8]
                                                      const float* __restrict__ als, // [N][4]
                                                      const float* __restrict__ ald, // [N][4]
                                                      const float* __restrict__ b0,  // [256]
                                                      uint2* __restrict__ h1s,       // [8][N][8]
                                                      int N){
  int t = threadIdx.x;
  int lane = t & 63;
  int li = t & 7;
  int p = blockIdx.x & 7;
  int head = p >> 1;
  int nbase = (blockIdx.x >> 3) * 128 + (t >> 3) * 4;
  const uint2* Hp = h0s + (size_t)p * N * 8;
  uint2* Op = h1s + (size_t)p * N * 8;
  float4 bb = ((const float4*)b0)[p * 8 + li];
  for(int j = 0; j < 4; j++){
    int n = nbase + j;
    if(n >= N) continue;
    int beg = rowptr[n], end = rowptr[n + 1];
    float adh = ald[(size_t)n * 4 + head];
    float4 acc = make_float4(0.f, 0.f, 0.f, 0.f);
    float den = 0.f;
    for(int c0 = beg; c0 < end; c0 += 8){
      int e = c0 + li;
      int s = n; float w = 0.f;
      if(e < end){
        s = esrc[e];
        w = expf(lrelu_f(als[(size_t)s * 4 + head] + adh));
      }
      int rem = end - c0;              // group-uniform
      if(rem > 8) rem = 8;
      #pragma unroll
      for(int g = 0; g < 2; g++){
        if(g * 4 < rem){
          #pragma unroll
          for(int ii = 0; ii < 4; ii++){
            int idx = (lane & 56) + g * 4 + ii;
            int si = __shfl(s, idx, 64);
            float wi = __shfl(w, idx, 64);
            uint2 v = Hp[(size_t)si * 8 + li];
            acc.x = fmaf(wi, b2f_lo(v.x), acc.x);
            acc.y = fmaf(wi, b2f_hi(v.x), acc.y);
            acc.z = fmaf(wi, b2f_lo(v.y), acc.z);
            acc.w = fmaf(wi, b2f_hi(v.y), acc.w);
            den += wi;
          }
        }
      }
    }
    float inv = 1.f / (den + 1e-16f);
    uint2 o;
    o.x = (unsigned)f2b(elu_f(acc.x * inv + bb.x)) |
          ((unsigned)f2b(elu_f(acc.y * inv + bb.y)) << 16);
    o.y = (unsigned)f2b(elu_f(acc.z * inv + bb.z)) |
          ((unsigned)f2b(elu_f(acc.w * inv + bb.w)) << 16);
    Op[(size_t)n * 8 + li] = o;
  }
}

// ---------------- GEMM1: g1b[M,64] = bf16(h1 @ W1) + logits ------------------
// A read from slice-major h1s [8][M][32]; slice = k0>>5.
__global__ __launch_bounds__(256) void gemm1_kernel(const ushort_t* __restrict__ h1s,
                                                    const ushort_t* __restrict__ Bp,
                                                    ushort_t* __restrict__ Cp,
                                                    const float* __restrict__ asrc,
                                                    const float* __restrict__ adst,
                                                    float* __restrict__ als,
                                                    float* __restrict__ ald, int M){
  int wave = threadIdx.x >> 6;
  int lane = threadIdx.x & 63;
  int tile0 = (blockIdx.x * 4 + wave) * 2;
  if(tile0 * 16 >= M) return;
  bool two = (tile0 + 1) * 16 < M;
  int m = lane & 15, q = lane >> 4;
  int r0 = tile0 * 16 + m;
  const ushort_t* Bq = Bp + (size_t)m * 256 + q * 8;
  f32x4 acc[2][4] = {};
  for(int k0 = 0; k0 < 256; k0 += 32){
    const ushort_t* Hk = h1s + (size_t)(k0 >> 5) * M * 32 + q * 8;
    short8 bv[4];
    #pragma unroll
    for(int j = 0; j < 4; j++) bv[j] = *(const short8*)(Bq + (size_t)j * 16 * 256 + k0);
    short8 a0 = *(const short8*)(Hk + (size_t)r0 * 32);
    #pragma unroll
    for(int j = 0; j < 4; j++)
      acc[0][j] = __builtin_amdgcn_mfma_f32_16x16x32_bf16(a0, bv[j], acc[0][j], 0, 0, 0);
    if(two){
      short8 a1 = *(const short8*)(Hk + (size_t)(r0 + 16) * 32);
      #pragma unroll
      for(int j = 0; j < 4; j++)
        acc[1][j] = __builtin_amdgcn_mfma_f32_16x16x32_bf16(a1, bv[j], acc[1][j], 0, 0, 0);
    }
  }
  #pragma unroll
  for(int r = 0; r < 2; r++){
    if(r == 1 && !two) break;
    int rowt = tile0 + r;
    #pragma unroll
    for(int j = 0; j < 4; j++){
      int col = j * 16 + m;
      #pragma unroll
      for(int i = 0; i < 4; i++){
        int rr = rowt * 16 + q * 4 + i;
        Cp[(size_t)rr * 64 + col] = f2b(acc[r][j][i]);
      }
    }
    float vs[4] = {0,0,0,0}, vd[4] = {0,0,0,0};
    #pragma unroll
    for(int j = 0; j < 4; j++){
      int col = j * 16 + m;
      float a_s = asrc[col], a_d = adst[col];
      #pragma unroll
      for(int i = 0; i < 4; i++){
        vs[i] = fmaf(acc[r][j][i], a_s, vs[i]);
        vd[i] = fmaf(acc[r][j][i], a_d, vd[i]);
      }
    }
    #pragma unroll
    for(int off = 8; off > 0; off >>= 1){
      #pragma unroll
      for(int i = 0; i < 4; i++){
        vs[i] += __shfl_down(vs[i], off, 16);
        vd[i] += __shfl_down(vd[i], off, 16);
      }
    }
    if(m == 0){
      #pragma unroll
      for(int i = 0; i < 4; i++){
        int rr = rowt * 16 + q * 4 + i;
        als[rr] = vs[i];
        ald[rr] = vd[i];
      }
    }
  }
}

// ---------------- agg1-L1 + GEMM2 fused --------------------------------------
#define H2S 72    // LDS h2 tile k-stride (shorts)
__global__ __launch_bounds__(256, 8) void agg1g2_kernel(const int* __restrict__ rowptr,
                                                        const int* __restrict__ esrc,
                                                        const uint2* __restrict__ g1b2,
                                                        const float* __restrict__ als1,
                                                        const float* __restrict__ ald1,
                                                        const float* __restrict__ b1,
                                                        const ushort_t* __restrict__ W2p,
                                                        const float* __restrict__ as2,
                                                        const float* __restrict__ ad2,
                                                        ushort_t* __restrict__ g2b,
                                                        float* __restrict__ als2,
                                                        float* __restrict__ ald2, int N){
  __shared__ ushort_t Hs[16 * H2S];
  __shared__ float aps[4][16], apd[4][16];
  int t = threadIdx.x;
  int wave = t >> 6, lane = t & 63;
  int nbase = blockIdx.x * 16;
  int g = lane >> 4;                 // group in wave
  int p = lane & 15;                 // lane in group
  int n = nbase + wave * 4 + g;
  int nl = wave * 4 + g;
  if(n < N){
    int beg = rowptr[n], end = rowptr[n + 1];
    float ad = ald1[n];
    float4 acc = make_float4(0.f, 0.f, 0.f, 0.f);
    float den = 0.f;
    for(int c0 = beg; c0 < end; c0 += 16){
      int e = c0 + p;
      int s = n; float w = 0.f;
      if(e < end){
        s = esrc[e];
        w = expf(lrelu_f(als1[s] + ad));
      }
      int rem = end - c0;            // group-uniform
      if(rem > 16) rem = 16;
      #pragma unroll
      for(int gg = 0; gg < 4; gg++){
        if(gg * 4 < rem){
          #pragma unroll
          for(int ii = 0; ii < 4; ii++){
            int i = gg * 4 + ii;
            int idx = (lane & 48) + i;
            int si = __shfl(s, idx, 64);
            float wi = __shfl(w, idx, 64);
            uint2 v = g1b2[((size_t)si << 4) + p];
            acc.x = fmaf(wi, b2f_lo(v.x), acc.x);
            acc.y = fmaf(wi, b2f_hi(v.x), acc.y);
            acc.z = fmaf(wi, b2f_lo(v.y), acc.z);
            acc.w = fmaf(wi, b2f_hi(v.y), acc.w);
            den += wi;
          }
        }
      }
    }
    float inv = 1.f / (den + 1e-16f);
    float4 bb = ((const float4*)b1)[p];
    unsigned o0 = (unsigned)f2b(elu_f(acc.x * inv + bb.x)) |
                  ((unsigned)f2b(elu_f(acc.y * inv + bb.y)) << 16);
    unsigned o1 = (unsigned)f2b(elu_f(acc.z * inv + bb.z)) |
                  ((unsigned)f2b(elu_f(acc.w * inv + bb.w)) << 16);
    uint2 ov; ov.x = o0; ov.y = o1;
    *(uint2*)(Hs + nl * H2S + p * 4) = ov;
  }
  __syncthreads();
  int m = lane & 15, q = lane >> 4;
  const ushort_t* Bw = W2p + (size_t)(wave * 16 + m) * 64 + q * 8;
  const ushort_t* Aw = Hs + m * H2S + q * 8;
  f32x4 acc = {};
  #pragma unroll
  for(int k0 = 0; k0 < 64; k0 += 32){
    short8 av = *(const short8*)(Aw + k0);
    short8 bv = *(const short8*)(Bw + k0);
    acc = __builtin_amdgcn_mfma_f32_16x16x32_bf16(av, bv, acc, 0, 0, 0);
  }
  float a_s = as2[wave * 16 + m], a_d = ad2[wave * 16 + m];
  float vs[4], vd[4];
  #pragma unroll
  for(int i = 0; i < 4; i++){
    int gn = nbase + q * 4 + i;
    if(gn < N) g2b[(size_t)gn * 64 + wave * 16 + m] = f2b(acc[i]);
    vs[i] = acc[i] * a_s;
    vd[i] = acc[i] * a_d;
  }
  #pragma unroll
  for(int off = 8; off > 0; off >>= 1){
    #pragma unroll
    for(int i = 0; i < 4; i++){
      vs[i] += __shfl_down(vs[i], off, 16);
      vd[i] += __shfl_down(vd[i], off, 16);
    }
  }
  if(m == 0){
    #pragma unroll
    for(int i = 0; i < 4; i++){
      aps[wave][q * 4 + i] = vs[i];
      apd[wave][q * 4 + i] = vd[i];
    }
  }
  __syncthreads();
  if(t < 16){
    int gn = nbase + t;
    if(gn < N){
      als2[gn] = aps[0][t] + aps[1][t] + aps[2][t] + aps[3][t];
      ald2[gn] = apd[0][t] + apd[1][t] + apd[2][t] + apd[3][t];
    }
  }
}

// ---------------- final agg (layer 2): 16-lane group per node, fp32 out ------
__global__ __launch_bounds__(256, 8) void aggF_kernel(const int* __restrict__ rowptr,
                                                      const int* __restrict__ esrc,
                                                      const uint2* __restrict__ gb2,
                                                      const float* __restrict__ als,
                                                      const float* __restrict__ ald,
                                                      const float* __restrict__ b,
                                                      float4* __restrict__ outp, int N){
  int t = threadIdx.x;
  int lane = t & 63;
  int g = lane >> 4;
  int p = lane & 15;
  int n = blockIdx.x * 16 + (t >> 6) * 4 + g;
  if(n >= N) return;
  int beg = rowptr[n], end = rowptr[n + 1];
  float ad = ald[n];
  float4 acc = make_float4(0.f, 0.f, 0.f, 0.f);
  float den = 0.f;
  for(int c0 = beg; c0 < end; c0 += 16){
    int e = c0 + p;
    int s = n; float w = 0.f;
    if(e < end){
      s = esrc[e];
      w = expf(lrelu_f(als[s] + ad));
    }
    int rem = end - c0;              // group-uniform
    if(rem > 16) rem = 16;
    #pragma unroll
    for(int gg = 0; gg < 4; gg++){
      if(gg * 4 < rem){
        #pragma unroll
        for(int ii = 0; ii < 4; ii++){
          int i = gg * 4 + ii;
          int idx = (lane & 48) + i;
          int si = __shfl(s, idx, 64);
          float wi = __shfl(w, idx, 64);
          uint2 v = gb2[((size_t)si << 4) + p];
          acc.x = fmaf(wi, b2f_lo(v.x), acc.x);
          acc.y = fmaf(wi, b2f_hi(v.x), acc.y);
          acc.z = fmaf(wi, b2f_lo(v.y), acc.z);
          acc.w = fmaf(wi, b2f_hi(v.y), acc.w);
          den += wi;
        }
      }
    }
  }
  float inv = 1.f / (den + 1e-16f);
  float4 bb = ((const float4*)b)[p];
  float4 o;
  o.x = elu_f(acc.x * inv + bb.x);
  o.y = elu_f(acc.y * inv + bb.y);
  o.z = elu_f(acc.z * inv + bb.z);
  o.w = elu_f(acc.w * inv + bb.w);
  outp[((size_t)n << 4) + p] = o;
}

extern "C" void kernel_launch(void* const* d_in, const int* in_sizes, int n_in,
                              void* d_out, int out_size, void* d_ws, size_t ws_size,
                              hipStream_t stream){
  const float* x   = (const float*)d_in[0];
  const int*   ei  = (const int*)d_in[1];
  const float* W0  = (const float*)d_in[2];
  const float* as0 = (const float*)d_in[3];
  const float* ad0 = (const float*)d_in[4];
  const float* b0  = (const float*)d_in[5];
  const float* W1  = (const float*)d_in[6];
  const float* as1 = (const float*)d_in[7];
  const float* ad1 = (const float*)d_in[8];
  const float* b1  = (const float*)d_in[9];
  const float* W2  = (const float*)d_in[10];
  const float* as2 = (const float*)d_in[11];
  const float* ad2 = (const float*)d_in[12];
  const float* b2  = (const float*)d_in[13];
  int N = in_sizes[0] / 256;
  int E = in_sizes[1] / 2;
  int Etot = E + N;

  size_t off = 0;
  auto alc = [&](size_t bytes) -> char* {
    char* p = (char*)d_ws + off;
    off += (bytes + 255) & ~(size_t)255;
    return p;
  };
  ushort_t* h0s   = (ushort_t*)alc((size_t)8 * N * 32 * 2); // slice-major h0; g2b+g1b alias
  ushort_t* h1s   = (ushort_t*)alc((size_t)8 * N * 32 * 2); // slice-major h1
  float*    als   = (float*)alc((size_t)N * 4 * 4);
  float*    ald   = (float*)alc((size_t)N * 4 * 4);
  float*    als1  = (float*)alc((size_t)N * 4);
  float*    ald1  = (float*)alc((size_t)N * 4);
  float*    als2  = (float*)alc((size_t)N * 4);
  float*    ald2  = (float*)alc((size_t)N * 4);
  int*      esrc  = (int*)alc((size_t)Etot * 4);
  int*      rowptr= (int*)alc((size_t)(N + 1) * 4);
  int*      cnt   = (int*)alc((size_t)N * 4);
  int*      cursor= (int*)alc((size_t)N * 4);
  int*      bsum  = (int*)alc(256 * 4);
  ushort_t* W0p   = (ushort_t*)alc(256 * 256 * 2);
  ushort_t* W1p   = (ushort_t*)alc(256 * 64 * 2);
  ushort_t* W2p   = (ushort_t*)alc(64 * 64 * 2);

  // h0s (25.6MB) dead after aggs; carve disjoint pieces for g2b and g1b:
  //   g2b = h0s[0 .. 6.4MB)        (written by agg1g2, read by aggF)
  //   g1b = h0s[12.8MB .. 19.2MB)  (written by gemm1, read by agg1g2)
  ushort_t* g2b = h0s;
  ushort_t* g1b = h0s + (size_t)4 * N * 32;

  int nb = (N + 255) / 256;                // <= 256 chunks
  int eb = (Etot + 255) / 256;
  int g0b = (N + 31) / 32;
  int rb = ((N / 16) + 7) / 8;
  int tb = (N + 15) / 16;
  int ab16 = (N + 15) / 16;
  int asb = ((N + 127) / 128) * 8;         // aggs: 8 slices x node-groups

  // ---- prep + CSR build ----
  hipMemsetAsync(cnt, 0, (size_t)N * 4, stream);
  prep_kernel<<<eb + 336, 256, 0, stream>>>(ei, cnt, W0, W0p, W1, W1p, W2, W2p,
                                            E, Etot, eb);
  blocksum_kernel<<<nb, 256, 0, stream>>>(cnt, bsum, N);
  scan2_kernel<<<nb, 256, 0, stream>>>(cnt, bsum, rowptr, cursor, N, Etot, nb);
  scatter_kernel<<<eb, 256, 0, stream>>>(ei, cursor, esrc, E, Etot);

  // ---- Layer 0 GEMM (reads x fp32 directly; writes slice-major h0s) ----
  gemm0_kernel<<<g0b, 256, 0, stream>>>((const float4*)x, W0p, h0s,
                                        as0, ad0, als, ald, N);

  // ---- Layer 0 agg, XCD channel-sliced ----
  aggs_kernel<<<asb, 256, 0, stream>>>(rowptr, esrc, (const uint2*)h0s,
                                       als, ald, b0, (uint2*)h1s, N);

  // ---- Layer 1 GEMM (A from slice-major h1s) ----
  gemm1_kernel<<<rb, 256, 0, stream>>>(h1s, W1p, g1b, as1, ad1, als1, ald1, N);

  // ---- Layer 1 agg + Layer 2 GEMM (fused) ----
  agg1g2_kernel<<<tb, 256, 0, stream>>>(rowptr, esrc, (const uint2*)g1b,
                                        als1, ald1, b1, W2p, as2, ad2,
                                        g2b, als2, ald2, N);

  // ---- Layer 2 agg -> output ----
  aggF_kernel<<<ab16, 256, 0, stream>>>(rowptr, esrc, (const uint2*)g2b,
                                        als2, ald2, b2, (float4*)d_out, N);
}

// Round 12
// 358.839 us; speedup vs baseline: 1.0951x; 1.0951x over previous
//
#include <hip/hip_runtime.h>
#include <hip/hip_bf16.h>

// ModifiedGAT, round 23 — REVERT to r20 (measured best, 355.0us).
//  - r22 post-mortem: XCD channel-slicing falsified by its own diagnostic
//    (aggs FETCH 194MB ~= no-locality 205MB, not ~60MB): blockIdx%8 does NOT
//    confine blocks to XCDs. Slicing also added 19MB writes + gemm1 dispatch
//    -> 393us total. Pre-committed abort executed.
//  - Evidence ledger: agg0g1 gather at compulsory-fetch floor (209-212MB =
//    h0 25.6MB x 8 XCD L2s @ 3.55-3.6TB/s; invariant across r11/13/14/18/20).
//    Fused agg0g1 ~= split agg0+gemm1. Remaining kernels individually <79us.
//  - Pipeline: memset | prep | blocksum | scan2 | scatter | gemm0 | agg0g1 |
//              agg1g2 | aggF  (9 dispatches).

typedef unsigned short ushort_t;
typedef __attribute__((ext_vector_type(8))) short short8;
typedef __attribute__((ext_vector_type(4))) float f32x4;

__device__ __forceinline__ float elu_f(float x){ return x > 0.f ? x : expm1f(x); }
__device__ __forceinline__ float lrelu_f(float x){ return x > 0.f ? x : 0.2f * x; }
__device__ __forceinline__ ushort_t f2b(float f){
  union { float f; unsigned u; } v; v.f = f;
  unsigned r = v.u + 0x7fff + ((v.u >> 16) & 1);   // round-to-nearest-even
  return (ushort_t)(r >> 16);
}
__device__ __forceinline__ float b2f_lo(unsigned v){
  union { unsigned u; float f; } c; c.u = v << 16; return c.f;
}
__device__ __forceinline__ float b2f_hi(unsigned v){
  union { unsigned u; float f; } c; c.u = v & 0xffff0000u; return c.f;
}

// ---------------- prep: hist + weight transposes -----------------------------
__global__ __launch_bounds__(256) void prep_kernel(const int* __restrict__ ei,
                                                   int* __restrict__ cnt,
                                                   const float* __restrict__ W0,
                                                   ushort_t* __restrict__ W0p,
                                                   const float* __restrict__ W1,
                                                   ushort_t* __restrict__ W1p,
                                                   const float* __restrict__ W2,
                                                   ushort_t* __restrict__ W2p,
                                                   int E, int Etot, int eb){
  int bid = blockIdx.x; int t = threadIdx.x;
  if(bid < eb){
    int e = bid * 256 + t;
    if(e < Etot){
      int d = (e < E) ? ei[E + e] : (e - E);
      atomicAdd(&cnt[d], 1);
    }
  } else {
    int r = bid - eb;
    if(r < 256){            // W0: 256x256
      int i = r * 256 + t; int k = i >> 8, n = i & 255;
      W0p[(size_t)n * 256 + k] = f2b(W0[i]);
    } else if(r < 320){     // W1: 256x64
      int i = (r - 256) * 256 + t; int k = i >> 6, n = i & 63;
      W1p[(size_t)n * 256 + k] = f2b(W1[i]);
    } else {                // W2: 64x64
      int i = (r - 320) * 256 + t; int k = i >> 6, n = i & 63;
      W2p[(size_t)n * 64 + k] = f2b(W2[i]);
    }
  }
}

// ---------------- CSR scan -----------------------------------------------------
__global__ __launch_bounds__(256) void blocksum_kernel(const int* __restrict__ cnt,
                                                       int* __restrict__ bsum, int N){
  __shared__ int sm[256];
  int t = threadIdx.x;
  int i = blockIdx.x * 256 + t;
  sm[t] = (i < N) ? cnt[i] : 0;
  __syncthreads();
  for(int off = 128; off > 0; off >>= 1){
    if(t < off) sm[t] += sm[t + off];
    __syncthreads();
  }
  if(t == 0) bsum[blockIdx.x] = sm[0];
}

// scan2 with internal bsum prefix (scanb folded in); nb <= 256.
__global__ __launch_bounds__(256) void scan2_kernel(const int* __restrict__ cnt,
                                                    const int* __restrict__ bsum,
                                                    int* __restrict__ rowptr,
                                                    int* __restrict__ cursor,
                                                    int N, int Etot, int nb){
  __shared__ int sm[256];
  __shared__ int spfx;
  int t = threadIdx.x;
  int c = blockIdx.x;
  sm[t] = (t < c && t < nb) ? bsum[t] : 0;
  __syncthreads();
  for(int off = 128; off > 0; off >>= 1){
    if(t < off) sm[t] += sm[t + off];
    __syncthreads();
  }
  if(t == 0) spfx = sm[0];
  __syncthreads();
  int pfx = spfx;
  __syncthreads();
  int i = c * 256 + t;
  int v = (i < N) ? cnt[i] : 0;
  sm[t] = v;
  __syncthreads();
  for(int off = 1; off < 256; off <<= 1){
    int x = 0;
    if(t >= off) x = sm[t - off];
    __syncthreads();
    sm[t] += x;
    __syncthreads();
  }
  if(i < N){
    int ex = sm[t] - v + pfx;
    rowptr[i] = ex;
    cursor[i] = ex;
    if(i == N - 1) rowptr[N] = Etot;
  }
}

__global__ __launch_bounds__(256) void scatter_kernel(const int* __restrict__ ei,
                                                      int* __restrict__ cursor,
                                                      int* __restrict__ esrc,
                                                      int E, int Etot){
  int e = blockIdx.x * 256 + threadIdx.x;
  if(e >= Etot) return;
  int s, d;
  if(e < E){ s = ei[e]; d = ei[E + e]; } else { s = e - E; d = s; }
  int pos = atomicAdd(&cursor[d], 1);
  esrc[pos] = s;
}

// ---------------- GEMM0: h0b[M,256] = bf16(x[M,256] @ W0) + logits ----------
// A staged directly from fp32 x (f2b during LDS fill) — no xb round-trip.
#define SKP 264   // padded LDS k-stride (shorts)
__global__ __launch_bounds__(256) void gemm0_kernel(const float4* __restrict__ x4,
                                                    const ushort_t* __restrict__ Bp,
                                                    ushort_t* __restrict__ h0b,
                                                    const float* __restrict__ asrc,
                                                    const float* __restrict__ adst,
                                                    float* __restrict__ als,
                                                    float* __restrict__ ald, int M){
  __shared__ ushort_t As[32 * SKP];
  int t = threadIdx.x;
  int row0 = blockIdx.x * 32;
  {
    int c = t;
    #pragma unroll
    for(int it = 0; it < 4; it++, c += 256){
      int r = c >> 5;
      int kc = (c & 31) << 3;          // col in shorts (multiple of 8)
      int gr = row0 + r;
      short8 v = {};
      if(gr < M){
        float4 f0 = x4[(size_t)gr * 64 + (kc >> 2)];
        float4 f1 = x4[(size_t)gr * 64 + (kc >> 2) + 1];
        v[0] = (short)f2b(f0.x); v[1] = (short)f2b(f0.y);
        v[2] = (short)f2b(f0.z); v[3] = (short)f2b(f0.w);
        v[4] = (short)f2b(f1.x); v[5] = (short)f2b(f1.y);
        v[6] = (short)f2b(f1.z); v[7] = (short)f2b(f1.w);
      }
      *(short8*)(As + r * SKP + kc) = v;
    }
  }
  __syncthreads();
  int wave = t >> 6, lane = t & 63;
  int m = lane & 15, q = lane >> 4;
  int colb = wave;                   // head
  const ushort_t* Bq = Bp + (size_t)(colb * 64 + m) * 256 + q * 8;
  const ushort_t* A0 = As + m * SKP + q * 8;
  const ushort_t* A1 = As + (16 + m) * SKP + q * 8;
  f32x4 acc[2][4] = {};
  for(int k0 = 0; k0 < 256; k0 += 32){
    short8 bv[4];
    #pragma unroll
    for(int j = 0; j < 4; j++) bv[j] = *(const short8*)(Bq + (size_t)j * 16 * 256 + k0);
    short8 a0 = *(const short8*)(A0 + k0);
    short8 a1 = *(const short8*)(A1 + k0);
    #pragma unroll
    for(int j = 0; j < 4; j++){
      acc[0][j] = __builtin_amdgcn_mfma_f32_16x16x32_bf16(a0, bv[j], acc[0][j], 0, 0, 0);
      acc[1][j] = __builtin_amdgcn_mfma_f32_16x16x32_bf16(a1, bv[j], acc[1][j], 0, 0, 0);
    }
  }
  #pragma unroll
  for(int rt = 0; rt < 2; rt++){
    #pragma unroll
    for(int j = 0; j < 4; j++){
      int col = colb * 64 + j * 16 + m;
      #pragma unroll
      for(int i = 0; i < 4; i++){
        int gr = row0 + rt * 16 + q * 4 + i;
        if(gr < M) h0b[(size_t)gr * 256 + col] = f2b(acc[rt][j][i]);
      }
    }
    float vs[4] = {0,0,0,0}, vd[4] = {0,0,0,0};
    #pragma unroll
    for(int j = 0; j < 4; j++){
      int col = colb * 64 + j * 16 + m;
      float a_s = asrc[col], a_d = adst[col];
      #pragma unroll
      for(int i = 0; i < 4; i++){
        vs[i] = fmaf(acc[rt][j][i], a_s, vs[i]);
        vd[i] = fmaf(acc[rt][j][i], a_d, vd[i]);
      }
    }
    #pragma unroll
    for(int off = 8; off > 0; off >>= 1){
      #pragma unroll
      for(int i = 0; i < 4; i++){
        vs[i] += __shfl_down(vs[i], off, 16);
        vd[i] += __shfl_down(vd[i], off, 16);
      }
    }
    if(m == 0){
      #pragma unroll
      for(int i = 0; i < 4; i++){
        int gr = row0 + rt * 16 + q * 4 + i;
        if(gr < M){
          als[(size_t)gr * 4 + colb] = vs[i];
          ald[(size_t)gr * 4 + colb] = vd[i];
        }
      }
    }
  }
}

// ---------------- agg0 + GEMM1 fused (16 nodes/block, r18 geometry) ----------
// Phase 1: wave w gathers nodes nbase+w*4..w*4+3 sequentially; h1 rows -> LDS.
// Phase 2: full 16x256 A tile; wave w computes cols w*16..w*16+15 via 8 MFMA;
//          emits g1b + layer-1 logits.
#define SKP2 264
__global__ __launch_bounds__(256, 8) void agg0g1_kernel(const int* __restrict__ rowptr,
                                                        const int* __restrict__ esrc,
                                                        const uint2* __restrict__ h0b2,
                                                        const float4* __restrict__ als4,
                                                        const float4* __restrict__ ald4,
                                                        const float4* __restrict__ b4,
                                                        const ushort_t* __restrict__ W1p,
                                                        const float* __restrict__ as1,
                                                        const float* __restrict__ ad1,
                                                        ushort_t* __restrict__ g1b,
                                                        float* __restrict__ als1,
                                                        float* __restrict__ ald1, int N){
  __shared__ ushort_t Hs[16 * SKP2];
  __shared__ float aps[4][16], apd[4][16];
  int t = threadIdx.x;
  int lane = t & 63;
  int wave = t >> 6;
  int nbase = blockIdx.x * 16;
  int h = lane >> 4;
  float4 bb = b4[lane];
  for(int j = 0; j < 4; j++){
    int n = nbase + wave * 4 + j;
    int nl = wave * 4 + j;
    uint2 o; o.x = 0u; o.y = 0u;
    if(n < N){
      int beg = rowptr[n], end = rowptr[n + 1];
      float adh = ((const float*)(ald4 + n))[h];
      float4 acc = make_float4(0.f, 0.f, 0.f, 0.f);
      float den = 0.f;
      for(int c0 = beg; c0 < end; c0 += 16){
        int e = c0 + (lane & 15);
        int s = n; float w = 0.f;
        if(e < end){
          s = esrc[e];
          w = expf(lrelu_f(((const float*)(als4 + s))[h] + adh));
        }
        int rem = end - c0;               // wave-uniform
        if(rem > 16) rem = 16;
        #pragma unroll
        for(int g = 0; g < 4; g++){
          if(g * 4 < rem){
            int si[4]; float wi[4]; uint2 v[4];
            #pragma unroll
            for(int ii = 0; ii < 4; ii++){
              int idx = (lane & 48) + g * 4 + ii;
              si[ii] = __shfl(s, idx, 64);
              wi[ii] = __shfl(w, idx, 64);
            }
            #pragma unroll
            for(int ii = 0; ii < 4; ii++)
              v[ii] = h0b2[((size_t)si[ii] << 6) + lane];
            #pragma unroll
            for(int ii = 0; ii < 4; ii++){
              acc.x = fmaf(wi[ii], b2f_lo(v[ii].x), acc.x);
              acc.y = fmaf(wi[ii], b2f_hi(v[ii].x), acc.y);
              acc.z = fmaf(wi[ii], b2f_lo(v[ii].y), acc.z);
              acc.w = fmaf(wi[ii], b2f_hi(v[ii].y), acc.w);
              den += wi[ii];
            }
          }
        }
      }
      float inv = 1.f / (den + 1e-16f);
      float v0 = elu_f(acc.x * inv + bb.x);
      float v1 = elu_f(acc.y * inv + bb.y);
      float v2 = elu_f(acc.z * inv + bb.z);
      float v3 = elu_f(acc.w * inv + bb.w);
      o.x = (unsigned)f2b(v0) | ((unsigned)f2b(v1) << 16);
      o.y = (unsigned)f2b(v2) | ((unsigned)f2b(v3) << 16);
    }
    *(uint2*)(Hs + nl * SKP2 + lane * 4) = o;
  }
  __syncthreads();
  // ---- phase 2: g1[16x64] = h1[16x256] @ W1 (per-wave 16-col quadrant) ----
  int m = lane & 15, q = lane >> 4;
  const ushort_t* Bw = W1p + (size_t)(wave * 16 + m) * 256 + q * 8;
  const ushort_t* Aw = Hs + m * SKP2 + q * 8;
  f32x4 acc1 = {};
  #pragma unroll
  for(int k0 = 0; k0 < 256; k0 += 32){
    short8 av = *(const short8*)(Aw + k0);
    short8 bv = *(const short8*)(Bw + k0);
    acc1 = __builtin_amdgcn_mfma_f32_16x16x32_bf16(av, bv, acc1, 0, 0, 0);
  }
  #pragma unroll
  for(int i = 0; i < 4; i++){
    int gn = nbase + q * 4 + i;
    if(gn < N) g1b[(size_t)gn * 64 + wave * 16 + m] = f2b(acc1[i]);
  }
  float a_s = as1[wave * 16 + m], a_d = ad1[wave * 16 + m];
  float vs[4], vd[4];
  #pragma unroll
  for(int i = 0; i < 4; i++){
    vs[i] = acc1[i] * a_s;
    vd[i] = acc1[i] * a_d;
  }
  #pragma unroll
  for(int off = 8; off > 0; off >>= 1){
    #pragma unroll
    for(int i = 0; i < 4; i++){
      vs[i] += __shfl_down(vs[i], off, 16);
      vd[i] += __shfl_down(vd[i], off, 16);
    }
  }
  if(m == 0){
    #pragma unroll
    for(int i = 0; i < 4; i++){
      aps[wave][q * 4 + i] = vs[i];
      apd[wave][q * 4 + i] = vd[i];
    }
  }
  __syncthreads();
  if(t < 16){
    int gn = nbase + t;
    if(gn < N){
      als1[gn] = aps[0][t] + aps[1][t] + aps[2][t] + aps[3][t];
      ald1[gn] = apd[0][t] + apd[1][t] + apd[2][t] + apd[3][t];
    }
  }
}

// ---------------- agg1-L1 + GEMM2 fused --------------------------------------
// L1 agg: one node per 16-lane group (4 nodes/wave, 16 nodes/block).
#define H2S 72    // LDS h2 tile k-stride (shorts)
__global__ __launch_bounds__(256, 8) void agg1g2_kernel(const int* __restrict__ rowptr,
                                                        const int* __restrict__ esrc,
                                                        const uint2* __restrict__ g1b2,
                                                        const float* __restrict__ als1,
                                                        const float* __restrict__ ald1,
                                                        const float* __restrict__ b1,
                                                        const ushort_t* __restrict__ W2p,
                                                        const float* __restrict__ as2,
                                                        const float* __restrict__ ad2,
                                                        ushort_t* __restrict__ g2b,
                                                        float* __restrict__ als2,
                                                        float* __restrict__ ald2, int N){
  __shared__ ushort_t Hs[16 * H2S];
  __shared__ float aps[4][16], apd[4][16];
  int t = threadIdx.x;
  int wave = t >> 6, lane = t & 63;
  int nbase = blockIdx.x * 16;
  int g = lane >> 4;                 // group in wave
  int p = lane & 15;                 // lane in group
  int n = nbase + wave * 4 + g;
  int nl = wave * 4 + g;
  if(n < N){
    int beg = rowptr[n], end = rowptr[n + 1];
    float ad = ald1[n];
    float4 acc = make_float4(0.f, 0.f, 0.f, 0.f);
    float den = 0.f;
    for(int c0 = beg; c0 < end; c0 += 16){
      int e = c0 + p;
      int s = n; float w = 0.f;
      if(e < end){
        s = esrc[e];
        w = expf(lrelu_f(als1[s] + ad));
      }
      int rem = end - c0;            // group-uniform
      if(rem > 16) rem = 16;
      #pragma unroll
      for(int gg = 0; gg < 4; gg++){
        if(gg * 4 < rem){
          #pragma unroll
          for(int ii = 0; ii < 4; ii++){
            int i = gg * 4 + ii;
            int idx = (lane & 48) + i;
            int si = __shfl(s, idx, 64);
            float wi = __shfl(w, idx, 64);
            uint2 v = g1b2[((size_t)si << 4) + p];
            acc.x = fmaf(wi, b2f_lo(v.x), acc.x);
            acc.y = fmaf(wi, b2f_hi(v.x), acc.y);
            acc.z = fmaf(wi, b2f_lo(v.y), acc.z);
            acc.w = fmaf(wi, b2f_hi(v.y), acc.w);
            den += wi;
          }
        }
      }
    }
    float inv = 1.f / (den + 1e-16f);
    float4 bb = ((const float4*)b1)[p];
    unsigned o0 = (unsigned)f2b(elu_f(acc.x * inv + bb.x)) |
                  ((unsigned)f2b(elu_f(acc.y * inv + bb.y)) << 16);
    unsigned o1 = (unsigned)f2b(elu_f(acc.z * inv + bb.z)) |
                  ((unsigned)f2b(elu_f(acc.w * inv + bb.w)) << 16);
    uint2 ov; ov.x = o0; ov.y = o1;
    *(uint2*)(Hs + nl * H2S + p * 4) = ov;
  }
  __syncthreads();
  int m = lane & 15, q = lane >> 4;
  const ushort_t* Bw = W2p + (size_t)(wave * 16 + m) * 64 + q * 8;
  const ushort_t* Aw = Hs + m * H2S + q * 8;
  f32x4 acc = {};
  #pragma unroll
  for(int k0 = 0; k0 < 64; k0 += 32){
    short8 av = *(const short8*)(Aw + k0);
    short8 bv = *(const short8*)(Bw + k0);
    acc = __builtin_amdgcn_mfma_f32_16x16x32_bf16(av, bv, acc, 0, 0, 0);
  }
  float a_s = as2[wave * 16 + m], a_d = ad2[wave * 16 + m];
  float vs[4], vd[4];
  #pragma unroll
  for(int i = 0; i < 4; i++){
    int gn = nbase + q * 4 + i;
    if(gn < N) g2b[(size_t)gn * 64 + wave * 16 + m] = f2b(acc[i]);
    vs[i] = acc[i] * a_s;
    vd[i] = acc[i] * a_d;
  }
  #pragma unroll
  for(int off = 8; off > 0; off >>= 1){
    #pragma unroll
    for(int i = 0; i < 4; i++){
      vs[i] += __shfl_down(vs[i], off, 16);
      vd[i] += __shfl_down(vd[i], off, 16);
    }
  }
  if(m == 0){
    #pragma unroll
    for(int i = 0; i < 4; i++){
      aps[wave][q * 4 + i] = vs[i];
      apd[wave][q * 4 + i] = vd[i];
    }
  }
  __syncthreads();
  if(t < 16){
    int gn = nbase + t;
    if(gn < N){
      als2[gn] = aps[0][t] + aps[1][t] + aps[2][t] + aps[3][t];
      ald2[gn] = apd[0][t] + apd[1][t] + apd[2][t] + apd[3][t];
    }
  }
}

// ---------------- final agg (layer 2): 16-lane group per node, fp32 out ------
__global__ __launch_bounds__(256, 8) void aggF_kernel(const int* __restrict__ rowptr,
                                                      const int* __restrict__ esrc,
                                                      const uint2* __restrict__ gb2,
                                                      const float* __restrict__ als,
                                                      const float* __restrict__ ald,
                                                      const float* __restrict__ b,
                                                      float4* __restrict__ outp, int N){
  int t = threadIdx.x;
  int lane = t & 63;
  int g = lane >> 4;
  int p = lane & 15;
  int n = blockIdx.x * 16 + (t >> 6) * 4 + g;
  if(n >= N) return;
  int beg = rowptr[n], end = rowptr[n + 1];
  float ad = ald[n];
  float4 acc = make_float4(0.f, 0.f, 0.f, 0.f);
  float den = 0.f;
  for(int c0 = beg; c0 < end; c0 += 16){
    int e = c0 + p;
    int s = n; float w = 0.f;
    if(e < end){
      s = esrc[e];
      w = expf(lrelu_f(als[s] + ad));
    }
    int rem = end - c0;              // group-uniform
    if(rem > 16) rem = 16;
    #pragma unroll
    for(int gg = 0; gg < 4; gg++){
      if(gg * 4 < rem){
        #pragma unroll
        for(int ii = 0; ii < 4; ii++){
          int i = gg * 4 + ii;
          int idx = (lane & 48) + i;
          int si = __shfl(s, idx, 64);
          float wi = __shfl(w, idx, 64);
          uint2 v = gb2[((size_t)si << 4) + p];
          acc.x = fmaf(wi, b2f_lo(v.x), acc.x);
          acc.y = fmaf(wi, b2f_hi(v.x), acc.y);
          acc.z = fmaf(wi, b2f_lo(v.y), acc.z);
          acc.w = fmaf(wi, b2f_hi(v.y), acc.w);
          den += wi;
        }
      }
    }
  }
  float inv = 1.f / (den + 1e-16f);
  float4 bb = ((const float4*)b)[p];
  float4 o;
  o.x = elu_f(acc.x * inv + bb.x);
  o.y = elu_f(acc.y * inv + bb.y);
  o.z = elu_f(acc.z * inv + bb.z);
  o.w = elu_f(acc.w * inv + bb.w);
  outp[((size_t)n << 4) + p] = o;
}

extern "C" void kernel_launch(void* const* d_in, const int* in_sizes, int n_in,
                              void* d_out, int out_size, void* d_ws, size_t ws_size,
                              hipStream_t stream){
  const float* x   = (const float*)d_in[0];
  const int*   ei  = (const int*)d_in[1];
  const float* W0  = (const float*)d_in[2];
  const float* as0 = (const float*)d_in[3];
  const float* ad0 = (const float*)d_in[4];
  const float* b0  = (const float*)d_in[5];
  const float* W1  = (const float*)d_in[6];
  const float* as1 = (const float*)d_in[7];
  const float* ad1 = (const float*)d_in[8];
  const float* b1  = (const float*)d_in[9];
  const float* W2  = (const float*)d_in[10];
  const float* as2 = (const float*)d_in[11];
  const float* ad2 = (const float*)d_in[12];
  const float* b2  = (const float*)d_in[13];
  int N = in_sizes[0] / 256;
  int E = in_sizes[1] / 2;
  int Etot = E + N;

  size_t off = 0;
  auto alc = [&](size_t bytes) -> char* {
    char* p = (char*)d_ws + off;
    off += (bytes + 255) & ~(size_t)255;
    return p;
  };
  ushort_t* g1b   = (ushort_t*)alc((size_t)N * 64 * 2);  // layer-1 gemm out
  ushort_t* h0b   = (ushort_t*)alc((size_t)N * 256 * 2); // h0 bf16; g2b aliases
  float*    als   = (float*)alc((size_t)N * 4 * 4);
  float*    ald   = (float*)alc((size_t)N * 4 * 4);
  float*    als1  = (float*)alc((size_t)N * 4);
  float*    ald1  = (float*)alc((size_t)N * 4);
  float*    als2  = (float*)alc((size_t)N * 4);
  float*    ald2  = (float*)alc((size_t)N * 4);
  int*      esrc  = (int*)alc((size_t)Etot * 4);
  int*      rowptr= (int*)alc((size_t)(N + 1) * 4);
  int*      cnt   = (int*)alc((size_t)N * 4);
  int*      cursor= (int*)alc((size_t)N * 4);
  int*      bsum  = (int*)alc(256 * 4);
  ushort_t* W0p   = (ushort_t*)alc(256 * 256 * 2);
  ushort_t* W1p   = (ushort_t*)alc(256 * 64 * 2);
  ushort_t* W2p   = (ushort_t*)alc(64 * 64 * 2);

  ushort_t* g2b = h0b;                     // h0b dead after agg0g1

  int nb = (N + 255) / 256;                // <= 256 chunks
  int eb = (Etot + 255) / 256;
  int g0b = (N + 31) / 32;
  int tb = (N + 15) / 16;
  int ab16 = (N + 15) / 16;

  // ---- prep + CSR build ----
  hipMemsetAsync(cnt, 0, (size_t)N * 4, stream);
  prep_kernel<<<eb + 336, 256, 0, stream>>>(ei, cnt, W0, W0p, W1, W1p, W2, W2p,
                                            E, Etot, eb);
  blocksum_kernel<<<nb, 256, 0, stream>>>(cnt, bsum, N);
  scan2_kernel<<<nb, 256, 0, stream>>>(cnt, bsum, rowptr, cursor, N, Etot, nb);
  scatter_kernel<<<eb, 256, 0, stream>>>(ei, cursor, esrc, E, Etot);

  // ---- Layer 0 GEMM (reads x fp32 directly) ----
  gemm0_kernel<<<g0b, 256, 0, stream>>>((const float4*)x, W0p, h0b,
                                        as0, ad0, als, ald, N);

  // ---- Layer 0 agg + Layer 1 GEMM (fused, 16 nodes/block) ----
  agg0g1_kernel<<<ab16, 256, 0, stream>>>(rowptr, esrc, (const uint2*)h0b,
                                          (const float4*)als, (const float4*)ald,
                                          (const float4*)b0, W1p, as1, ad1,
                                          g1b, als1, ald1, N);

  // ---- Layer 1 agg + Layer 2 GEMM (fused) ----
  agg1g2_kernel<<<tb, 256, 0, stream>>>(rowptr, esrc, (const uint2*)g1b,
                                        als1, ald1, b1, W2p, as2, ad2,
                                        g2b, als2, ald2, N);

  // ---- Layer 2 agg -> output ----
  aggF_kernel<<<ab16, 256, 0, stream>>>(rowptr, esrc, (const uint2*)g2b,
                                        als2, ald2, b2, (float4*)d_out, N);
}